// Round 11
// baseline (312.704 us; speedup 1.0000x reference)
//
#include <hip/hip_runtime.h>
#include <math.h>

// ---------------------------------------------------------------------------
// 2-layer GraphSAGE (mean agg), fp32, MI355X.  R10 (resubmit — R10 bench
// never acquired a GPU):
//
//   R9 results: total 391 -> 306us. Bucketed build (k_b1+k_b2) works — both
//   below top-5 cutoff. New bottleneck: k_agg 57.5us x2, VGPR=24(!),
//   VALUBusy 15%, counted fetch 3.6 TB/s. The (256,6) bound made the
//   allocator serialize row loads (~1-2 in flight) -> latency-bound.
//
//   R10 change (k_agg only, everything else frozen for attribution):
//    - explicit 8-row load batch per iteration (8 independent float4 loads
//      in flight), plain __launch_bounds__(256) (no min-waves: let the
//      allocator keep ~75 VGPRs; R2/R9 lesson: min-waves collapses ILP).
//    - index broadcast via same-address scalar loads (L1 broadcast) instead
//      of shfl/ds_bpermute — removes lgkm dependency from the address path.
//   Prediction: k_agg 57.5 -> 30-40us, VGPR ~70-110, fetch BW 5-6 TB/s.
//   If it stays >=50us with deep pipeline: L3 gather ceiling found -> bf16.
// ---------------------------------------------------------------------------

#define PAD 48        // padded-fallback row capacity
#define BSH 9         // 512 nodes per bucket
#define BNODES 512
#define CAP 10240     // edges per bucket region (mean 8192, +22 sigma)
#define B1CHUNK 4096

__global__ void k_zero(int* __restrict__ p, int n) {
    int i = blockIdx.x * blockDim.x + threadIdx.x;
    int stride = gridDim.x * blockDim.x;
    for (; i < n; i += stride) p[i] = 0;
}

// ---- bucketed build, pass 1: scatter (src,tgt) into bucket regions ----
__global__ __launch_bounds__(256) void k_b1(
    const int* __restrict__ src, const int* __restrict__ tgt, int E,
    int* __restrict__ bcnt, int2* __restrict__ pairs) {
    __shared__ int bc[256];
    const int tid = threadIdx.x;
    bc[tid] = 0;
    __syncthreads();
    const int e0 = blockIdx.x * B1CHUNK;
    const int e1 = min(e0 + B1CHUNK, E);
    for (int i = e0 + tid; i < e1; i += 256)
        atomicAdd(&bc[tgt[i] >> BSH], 1);
    __syncthreads();
    const int mycnt = bc[tid];               // own slot only
    int gb = 0;
    if (mycnt > 0) gb = tid * CAP + atomicAdd(&bcnt[tid], mycnt);
    bc[tid] = gb;                            // reuse as global cursor (own slot)
    __syncthreads();
    for (int i = e0 + tid; i < e1; i += 256) {
        const int t = tgt[i];
        const int bk = t >> BSH;
        const int p = atomicAdd(&bc[bk], 1);
        if (p < (bk + 1) * CAP)              // statistically impossible to fail
            pairs[p] = make_int2(src[i], t);
    }
}

// ---- bucketed build, pass 2: per-bucket CSR in LDS, coalesced writes ----
__global__ __launch_bounds__(512) void k_b2(
    const int2* __restrict__ pairs, const int* __restrict__ bcnt,
    int* __restrict__ cnt, int* __restrict__ rowstart,
    int* __restrict__ colsrc, int N) {
    __shared__ int cnt_l[BNODES];
    __shared__ int row_l[BNODES];
    __shared__ int cur_l[BNODES];
    __shared__ int colsrc_l[CAP];

    const int b = blockIdx.x;
    const int tid = threadIdx.x;
    const int base = b * CAP;
    const int bc = min(bcnt[b], CAP);

    cnt_l[tid] = 0;
    __syncthreads();
    for (int j = tid; j < bc; j += 512)
        atomicAdd(&cnt_l[pairs[base + j].y & (BNODES - 1)], 1);
    __syncthreads();

    // exclusive scan of cnt_l (Hillis-Steele, 512 threads / 512 elems)
    row_l[tid] = cnt_l[tid];
    __syncthreads();
    for (int off = 1; off < BNODES; off <<= 1) {
        const int t = (tid >= off) ? row_l[tid - off] : 0;
        __syncthreads();
        row_l[tid] += t;
        __syncthreads();
    }
    row_l[tid] -= cnt_l[tid];                // inclusive -> exclusive (own slot)
    cur_l[tid] = row_l[tid];
    __syncthreads();

    for (int j = tid; j < bc; j += 512) {
        const int2 e = pairs[base + j];
        const int p = atomicAdd(&cur_l[e.y & (BNODES - 1)], 1);
        colsrc_l[p] = e.x;
    }
    __syncthreads();

    for (int j = tid; j < bc; j += 512) colsrc[base + j] = colsrc_l[j];
    const int node = b * BNODES + tid;
    if (node < N) {
        cnt[node] = cnt_l[tid];
        rowstart[node] = base + row_l[tid];
    }
}

// ---- padded one-pass build (fallback when bucket path doesn't fit) ----
__global__ void k_build(const int* __restrict__ src, const int* __restrict__ tgt, int E,
                        int* __restrict__ cnt, int* __restrict__ colpad) {
    int i = blockIdx.x * blockDim.x + threadIdx.x;
    int stride = gridDim.x * blockDim.x;
    for (; i < E; i += stride) {
        const int t = tgt[i];
        const int p = atomicAdd(&cnt[t], 1);
        if (p < PAD) colpad[(size_t)t * PAD + p] = src[i];
    }
}

// ---- gather-mean: agg[v] = mean_{s in N(v)} in[s] ----
// 16 nodes/block, 16 threads/node (float4 each). No LDS.
// 8 independent row loads in flight per iteration; no min-waves bound so
// the allocator keeps the pipeline in registers (R2/R9 lesson).
__global__ __launch_bounds__(256) void k_agg(
    const float* __restrict__ in, const int* __restrict__ rowstart,
    const int* __restrict__ cnt, const int* __restrict__ cols,
    float* __restrict__ agg, int N) {
    const int tid = threadIdx.x;
    const int g = tid >> 4;
    const int t = tid & 15;
    const int node = blockIdx.x * 16 + g;
    const bool valid = node < N;
    const int c4 = t * 4;

    int rs = 0, deg = 0;
    if (valid) {
        rs = rowstart ? rowstart[node] : node * PAD;
        deg = cnt[node];
    }
    const int degl = rowstart ? deg : min(deg, PAD);

    float4 a0 = {0,0,0,0}, a1 = {0,0,0,0}, a2 = {0,0,0,0}, a3 = {0,0,0,0};

    int e = 0;
    for (; e + 8 <= degl; e += 8) {
        // 8 index loads: same address across the 16-lane group -> L1 broadcast
        const int s0 = cols[rs + e + 0];
        const int s1 = cols[rs + e + 1];
        const int s2 = cols[rs + e + 2];
        const int s3 = cols[rs + e + 3];
        const int s4 = cols[rs + e + 4];
        const int s5 = cols[rs + e + 5];
        const int s6 = cols[rs + e + 6];
        const int s7 = cols[rs + e + 7];
        // 8 independent 16B row loads in flight
        const float4 v0 = *(const float4*)(in + (size_t)s0 * 64 + c4);
        const float4 v1 = *(const float4*)(in + (size_t)s1 * 64 + c4);
        const float4 v2 = *(const float4*)(in + (size_t)s2 * 64 + c4);
        const float4 v3 = *(const float4*)(in + (size_t)s3 * 64 + c4);
        const float4 v4 = *(const float4*)(in + (size_t)s4 * 64 + c4);
        const float4 v5 = *(const float4*)(in + (size_t)s5 * 64 + c4);
        const float4 v6 = *(const float4*)(in + (size_t)s6 * 64 + c4);
        const float4 v7 = *(const float4*)(in + (size_t)s7 * 64 + c4);
        a0.x += v0.x + v4.x; a0.y += v0.y + v4.y; a0.z += v0.z + v4.z; a0.w += v0.w + v4.w;
        a1.x += v1.x + v5.x; a1.y += v1.y + v5.y; a1.z += v1.z + v5.z; a1.w += v1.w + v5.w;
        a2.x += v2.x + v6.x; a2.y += v2.y + v6.y; a2.z += v2.z + v6.z; a2.w += v2.w + v6.w;
        a3.x += v3.x + v7.x; a3.y += v3.y + v7.y; a3.z += v3.z + v7.z; a3.w += v3.w + v7.w;
    }
    for (; e < degl; ++e) {
        const int s0 = cols[rs + e];
        const float4 v0 = *(const float4*)(in + (size_t)s0 * 64 + c4);
        a0.x += v0.x; a0.y += v0.y; a0.z += v0.z; a0.w += v0.w;
    }

    if (valid) {
        const float inv = deg > 0 ? 1.0f / (float)deg : 0.0f;
        float4 o;
        o.x = ((a0.x + a1.x) + (a2.x + a3.x)) * inv;
        o.y = ((a0.y + a1.y) + (a2.y + a3.y)) * inv;
        o.z = ((a0.z + a1.z) + (a2.z + a3.z)) * inv;
        o.w = ((a0.w + a1.w) + (a2.w + a3.w)) * inv;
        *(float4*)(agg + (size_t)node * 64 + c4) = o;
    }
}

// ---- fused GEMM (unchanged R5/R9) ----
template<int COUT>
__global__ __launch_bounds__(512, 6) void k_gemm(
    const float* __restrict__ agg, const float* __restrict__ xin,
    const float* __restrict__ Wl, const float* __restrict__ bias,
    const float* __restrict__ Wr, float* __restrict__ out, int N) {
    __shared__ float sWl[64 * COUT];
    __shared__ float sWr[64 * COUT];
    __shared__ float sA[32][68];
    __shared__ float sX[32][68];

    const int tid = threadIdx.x;
    for (int i = tid; i < 64 * COUT / 4; i += 512) {
        ((float4*)sWl)[i] = ((const float4*)Wl)[i];
        ((float4*)sWr)[i] = ((const float4*)Wr)[i];
    }

    const int g = tid >> 4;
    const int t = tid & 15;
    const int node = blockIdx.x * 32 + g;
    const int c4 = t * 4;

    if (node < N) {
        *(float4*)&sA[g][c4] = *(const float4*)(agg + (size_t)node * 64 + c4);
        *(float4*)&sX[g][c4] = *(const float4*)(xin + (size_t)node * 64 + c4);
    }
    __syncthreads();

    if (node < N) {
        if (COUT == 64) {
            float o0 = bias[c4], o1 = bias[c4 + 1], o2 = bias[c4 + 2], o3 = bias[c4 + 3];
#pragma unroll 8
            for (int k = 0; k < 64; ++k) {
                const float a = sA[g][k];
                const float xv = sX[g][k];
                const float4 wl = *(const float4*)&sWl[k * 64 + c4];
                const float4 wr = *(const float4*)&sWr[k * 64 + c4];
                o0 += a * wl.x + xv * wr.x;
                o1 += a * wl.y + xv * wr.y;
                o2 += a * wl.z + xv * wr.z;
                o3 += a * wl.w + xv * wr.w;
            }
            float4 o;
            o.x = o0 > 0.f ? o0 : 0.01f * o0;
            o.y = o1 > 0.f ? o1 : 0.01f * o1;
            o.z = o2 > 0.f ? o2 : 0.01f * o2;
            o.w = o3 > 0.f ? o3 : 0.01f * o3;
            *(float4*)(out + (size_t)node * 64 + c4) = o;
        } else {
            const int c2 = t * 2;
            float o0 = bias[c2], o1 = bias[c2 + 1];
#pragma unroll 8
            for (int k = 0; k < 64; ++k) {
                const float a = sA[g][k];
                const float xv = sX[g][k];
                const float2 wl = *(const float2*)&sWl[k * COUT + c2];
                const float2 wr = *(const float2*)&sWr[k * COUT + c2];
                o0 += a * wl.x + xv * wr.x;
                o1 += a * wl.y + xv * wr.y;
            }
            float2 o;
            o.x = o0 > 0.f ? o0 : 0.01f * o0;
            o.y = o1 > 0.f ? o1 : 0.01f * o1;
            *(float2*)(out + (size_t)node * COUT + c2) = o;
        }
    }
}

static inline size_t align256(size_t v) { return (v + 255) & ~(size_t)255; }

extern "C" void kernel_launch(void* const* d_in, const int* in_sizes, int n_in,
                              void* d_out, int out_size, void* d_ws, size_t ws_size,
                              hipStream_t stream) {
    const float* x   = (const float*)d_in[0];
    const int* edge  = (const int*)d_in[1];   // [2,E] int32
    const float* W1l = (const float*)d_in[2];
    const float* b1  = (const float*)d_in[3];
    const float* W1r = (const float*)d_in[4];
    const float* W2l = (const float*)d_in[5];
    const float* b2  = (const float*)d_in[6];
    const float* W2r = (const float*)d_in[7];
    float* out = (float*)d_out;

    const int N = in_sizes[0] / 64;
    const int E = in_sizes[1] / 2;
    const int* src = edge;
    const int* tgt = edge + E;

    char* ws = (char*)d_ws;
    size_t off = 0;
    int* cnt = (int*)(ws + off);     off = align256(off + (size_t)N * 4);
    float* agg = (float*)(ws + off); off = align256(off + (size_t)N * 64 * 4);
    const size_t h_off = off;
    float* h = (float*)(ws + off);   off = align256(off + (size_t)N * 64 * 4);

    const int nbuck = (N + BNODES - 1) >> BSH;
    const double meanb = (double)E / (double)(nbuck > 0 ? nbuck : 1);
    const bool shape_ok = nbuck >= 1 && nbuck <= 256 &&
                          meanb + 8.0 * sqrt(meanb) + 64.0 <= (double)CAP &&
                          (size_t)nbuck * CAP * 8 <= (size_t)N * 64 * 4;  // pairs fit in h

    size_t ob = off;
    int* rowstart = (int*)(ws + ob); ob = align256(ob + (size_t)N * 4);
    int* colsrc   = (int*)(ws + ob); ob = align256(ob + (size_t)nbuck * CAP * 4);
    int* bcnt     = (int*)(ws + ob); ob = align256(ob + 256 * 4);
    const bool use_bucket = shape_ok && ws_size >= ob;

    const int* rowstart_arg;
    const int* cols_arg;

    if (use_bucket) {
        int2* pairs = (int2*)(ws + h_off);      // aliases h (disjoint live range)
        k_zero<<<1, 256, 0, stream>>>(bcnt, 256);
        k_b1<<<(E + B1CHUNK - 1) / B1CHUNK, 256, 0, stream>>>(src, tgt, E, bcnt, pairs);
        k_b2<<<nbuck, 512, 0, stream>>>(pairs, bcnt, cnt, rowstart, colsrc, N);
        rowstart_arg = rowstart;
        cols_arg = colsrc;
    } else {
        int* colpad = (int*)(ws + off);
        k_zero<<<512, 256, 0, stream>>>(cnt, N);
        k_build<<<2048, 256, 0, stream>>>(src, tgt, E, cnt, colpad);
        rowstart_arg = nullptr;
        cols_arg = colpad;
    }

    const int nbA = (N + 15) / 16;
    const int nbG = (N + 31) / 32;

    k_agg<<<nbA, 256, 0, stream>>>(x, rowstart_arg, cnt, cols_arg, agg, N);
    k_gemm<64><<<nbG, 512, 0, stream>>>(agg, x, W1l, b1, W1r, h, N);
    k_agg<<<nbA, 256, 0, stream>>>(h, rowstart_arg, cnt, cols_arg, agg, N);
    k_gemm<32><<<nbG, 512, 0, stream>>>(agg, h, W2l, b2, W2r, out, N);
}

// Round 12
// 274.724 us; speedup vs baseline: 1.1383x; 1.1383x over previous
//
#include <hip/hip_runtime.h>
#include <hip/hip_bf16.h>
#include <math.h>

// ---------------------------------------------------------------------------
// 2-layer GraphSAGE (mean agg), MI355X.  R12:
//
//   R9/R11 evidence: k_agg pinned at ~58-61us across two different ILP
//   structures, FETCH ~177-182MB both, fill rate ~3.2 TB/s both. Model:
//   every XCD pulls ~all of x through its private L2 (8 x 25.6MB = 205MB
//   compulsory ~= measured FETCH); L3->L2 path saturates at ~3.2 TB/s.
//   Only lever: fewer bytes. R12 = bf16 GATHER OPERAND (compute stays fp32):
//     k_cvt     : x -> xb (bf16, RNE), 12.8MB
//     k_agg     : gathers 128B bf16 rows, fp32 accumulate
//     k_gemm64  : reads agg(fp32)+x(fp32 self term), writes h as BF16 (fused)
//     k_gemm32  : reads agg(fp32)+hb(bf16 self term), writes fp32 out
//   Buffer reuse: pairs (dies k_b2) -> xb (dies agg1) -> hb share one 25.6MB
//   region => workspace unchanged (~60MB). CSR build unchanged from R9.
//   Prediction: k_agg 60 -> 30-36us, FETCH -> ~95MB. absmax 0.0039 -> ~0.01.
//   Pre-commit: if validation fails, revert bf16; attack k_b2/gemm tail.
// ---------------------------------------------------------------------------

#define PAD 48        // padded-fallback row capacity
#define BSH 9         // 512 nodes per bucket
#define BNODES 512
#define CAP 10240     // edges per bucket region (mean 8192, +22 sigma)
#define B1CHUNK 4096

static __device__ __forceinline__ ushort f2bf(float f) {
    __hip_bfloat16 b = __float2bfloat16(f);   // RNE
    return *reinterpret_cast<ushort*>(&b);
}
static __device__ __forceinline__ float bf2f(ushort u) {
    union { unsigned int i; float f; } c;
    c.i = ((unsigned int)u) << 16;
    return c.f;
}

__global__ void k_zero(int* __restrict__ p, int n) {
    int i = blockIdx.x * blockDim.x + threadIdx.x;
    int stride = gridDim.x * blockDim.x;
    for (; i < n; i += stride) p[i] = 0;
}

// ---- fp32 -> bf16 row conversion (n4 = count of float4 groups) ----
__global__ void k_cvt(const float* __restrict__ in, ushort* __restrict__ outb, int n4) {
    int i = blockIdx.x * blockDim.x + threadIdx.x;
    int stride = gridDim.x * blockDim.x;
    for (; i < n4; i += stride) {
        const float4 v = ((const float4*)in)[i];
        ushort4 u;
        u.x = f2bf(v.x); u.y = f2bf(v.y); u.z = f2bf(v.z); u.w = f2bf(v.w);
        ((ushort4*)outb)[i] = u;
    }
}

// ---- bucketed build, pass 1 (unchanged R9) ----
__global__ __launch_bounds__(256) void k_b1(
    const int* __restrict__ src, const int* __restrict__ tgt, int E,
    int* __restrict__ bcnt, int2* __restrict__ pairs) {
    __shared__ int bc[256];
    const int tid = threadIdx.x;
    bc[tid] = 0;
    __syncthreads();
    const int e0 = blockIdx.x * B1CHUNK;
    const int e1 = min(e0 + B1CHUNK, E);
    for (int i = e0 + tid; i < e1; i += 256)
        atomicAdd(&bc[tgt[i] >> BSH], 1);
    __syncthreads();
    const int mycnt = bc[tid];
    int gb = 0;
    if (mycnt > 0) gb = tid * CAP + atomicAdd(&bcnt[tid], mycnt);
    bc[tid] = gb;
    __syncthreads();
    for (int i = e0 + tid; i < e1; i += 256) {
        const int t = tgt[i];
        const int bk = t >> BSH;
        const int p = atomicAdd(&bc[bk], 1);
        if (p < (bk + 1) * CAP)
            pairs[p] = make_int2(src[i], t);
    }
}

// ---- bucketed build, pass 2 (unchanged R9) ----
__global__ __launch_bounds__(512) void k_b2(
    const int2* __restrict__ pairs, const int* __restrict__ bcnt,
    int* __restrict__ cnt, int* __restrict__ rowstart,
    int* __restrict__ colsrc, int N) {
    __shared__ int cnt_l[BNODES];
    __shared__ int row_l[BNODES];
    __shared__ int cur_l[BNODES];
    __shared__ int colsrc_l[CAP];

    const int b = blockIdx.x;
    const int tid = threadIdx.x;
    const int base = b * CAP;
    const int bc = min(bcnt[b], CAP);

    cnt_l[tid] = 0;
    __syncthreads();
    for (int j = tid; j < bc; j += 512)
        atomicAdd(&cnt_l[pairs[base + j].y & (BNODES - 1)], 1);
    __syncthreads();

    row_l[tid] = cnt_l[tid];
    __syncthreads();
    for (int off = 1; off < BNODES; off <<= 1) {
        const int t = (tid >= off) ? row_l[tid - off] : 0;
        __syncthreads();
        row_l[tid] += t;
        __syncthreads();
    }
    row_l[tid] -= cnt_l[tid];
    cur_l[tid] = row_l[tid];
    __syncthreads();

    for (int j = tid; j < bc; j += 512) {
        const int2 e = pairs[base + j];
        const int p = atomicAdd(&cur_l[e.y & (BNODES - 1)], 1);
        colsrc_l[p] = e.x;
    }
    __syncthreads();

    for (int j = tid; j < bc; j += 512) colsrc[base + j] = colsrc_l[j];
    const int node = b * BNODES + tid;
    if (node < N) {
        cnt[node] = cnt_l[tid];
        rowstart[node] = base + row_l[tid];
    }
}

// ---- padded one-pass build (fallback) ----
__global__ void k_build(const int* __restrict__ src, const int* __restrict__ tgt, int E,
                        int* __restrict__ cnt, int* __restrict__ colpad) {
    int i = blockIdx.x * blockDim.x + threadIdx.x;
    int stride = gridDim.x * blockDim.x;
    for (; i < E; i += stride) {
        const int t = tgt[i];
        const int p = atomicAdd(&cnt[t], 1);
        if (p < PAD) colpad[(size_t)t * PAD + p] = src[i];
    }
}

// ---- gather-mean over bf16 rows: agg[v] = mean_{s in N(v)} inb[s] ----
// 16 nodes/block, 16 threads/node; each lane owns 4 cols -> ushort4 (8B).
// 8 independent row loads in flight; fp32 accumulate.
__global__ __launch_bounds__(256) void k_agg(
    const ushort* __restrict__ inb, const int* __restrict__ rowstart,
    const int* __restrict__ cnt, const int* __restrict__ cols,
    float* __restrict__ agg, int N) {
    const int tid = threadIdx.x;
    const int g = tid >> 4;
    const int t = tid & 15;
    const int node = blockIdx.x * 16 + g;
    const bool valid = node < N;
    const int c4 = t * 4;

    int rs = 0, deg = 0;
    if (valid) {
        rs = rowstart ? rowstart[node] : node * PAD;
        deg = cnt[node];
    }
    const int degl = rowstart ? deg : min(deg, PAD);

    float4 a0 = {0,0,0,0}, a1 = {0,0,0,0}, a2 = {0,0,0,0}, a3 = {0,0,0,0};

    int e = 0;
    for (; e + 8 <= degl; e += 8) {
        const int s0 = cols[rs + e + 0];
        const int s1 = cols[rs + e + 1];
        const int s2 = cols[rs + e + 2];
        const int s3 = cols[rs + e + 3];
        const int s4 = cols[rs + e + 4];
        const int s5 = cols[rs + e + 5];
        const int s6 = cols[rs + e + 6];
        const int s7 = cols[rs + e + 7];
        const ushort4 u0 = *(const ushort4*)(inb + (size_t)s0 * 64 + c4);
        const ushort4 u1 = *(const ushort4*)(inb + (size_t)s1 * 64 + c4);
        const ushort4 u2 = *(const ushort4*)(inb + (size_t)s2 * 64 + c4);
        const ushort4 u3 = *(const ushort4*)(inb + (size_t)s3 * 64 + c4);
        const ushort4 u4 = *(const ushort4*)(inb + (size_t)s4 * 64 + c4);
        const ushort4 u5 = *(const ushort4*)(inb + (size_t)s5 * 64 + c4);
        const ushort4 u6 = *(const ushort4*)(inb + (size_t)s6 * 64 + c4);
        const ushort4 u7 = *(const ushort4*)(inb + (size_t)s7 * 64 + c4);
        a0.x += bf2f(u0.x) + bf2f(u4.x); a0.y += bf2f(u0.y) + bf2f(u4.y);
        a0.z += bf2f(u0.z) + bf2f(u4.z); a0.w += bf2f(u0.w) + bf2f(u4.w);
        a1.x += bf2f(u1.x) + bf2f(u5.x); a1.y += bf2f(u1.y) + bf2f(u5.y);
        a1.z += bf2f(u1.z) + bf2f(u5.z); a1.w += bf2f(u1.w) + bf2f(u5.w);
        a2.x += bf2f(u2.x) + bf2f(u6.x); a2.y += bf2f(u2.y) + bf2f(u6.y);
        a2.z += bf2f(u2.z) + bf2f(u6.z); a2.w += bf2f(u2.w) + bf2f(u6.w);
        a3.x += bf2f(u3.x) + bf2f(u7.x); a3.y += bf2f(u3.y) + bf2f(u7.y);
        a3.z += bf2f(u3.z) + bf2f(u7.z); a3.w += bf2f(u3.w) + bf2f(u7.w);
    }
    for (; e < degl; ++e) {
        const int s0 = cols[rs + e];
        const ushort4 u0 = *(const ushort4*)(inb + (size_t)s0 * 64 + c4);
        a0.x += bf2f(u0.x); a0.y += bf2f(u0.y); a0.z += bf2f(u0.z); a0.w += bf2f(u0.w);
    }

    if (valid) {
        const float inv = deg > 0 ? 1.0f / (float)deg : 0.0f;
        float4 o;
        o.x = ((a0.x + a1.x) + (a2.x + a3.x)) * inv;
        o.y = ((a0.y + a1.y) + (a2.y + a3.y)) * inv;
        o.z = ((a0.z + a1.z) + (a2.z + a3.z)) * inv;
        o.w = ((a0.w + a1.w) + (a2.w + a3.w)) * inv;
        *(float4*)(agg + (size_t)node * 64 + c4) = o;
    }
}

// ---- layer-1 GEMM: hb = bf16(lrelu(agg@Wl + b + x@Wr)), x fp32 ----
__global__ __launch_bounds__(512, 6) void k_gemm64(
    const float* __restrict__ agg, const float* __restrict__ xin,
    const float* __restrict__ Wl, const float* __restrict__ bias,
    const float* __restrict__ Wr, ushort* __restrict__ outb, int N) {
    __shared__ float sWl[64 * 64];
    __shared__ float sWr[64 * 64];
    __shared__ float sA[32][68];
    __shared__ float sX[32][68];

    const int tid = threadIdx.x;
    for (int i = tid; i < 1024; i += 512) {
        ((float4*)sWl)[i] = ((const float4*)Wl)[i];
        ((float4*)sWr)[i] = ((const float4*)Wr)[i];
    }

    const int g = tid >> 4;
    const int t = tid & 15;
    const int node = blockIdx.x * 32 + g;
    const int c4 = t * 4;

    if (node < N) {
        *(float4*)&sA[g][c4] = *(const float4*)(agg + (size_t)node * 64 + c4);
        *(float4*)&sX[g][c4] = *(const float4*)(xin + (size_t)node * 64 + c4);
    }
    __syncthreads();

    if (node < N) {
        float o0 = bias[c4], o1 = bias[c4 + 1], o2 = bias[c4 + 2], o3 = bias[c4 + 3];
#pragma unroll 8
        for (int k = 0; k < 64; ++k) {
            const float a = sA[g][k];
            const float xv = sX[g][k];
            const float4 wl = *(const float4*)&sWl[k * 64 + c4];
            const float4 wr = *(const float4*)&sWr[k * 64 + c4];
            o0 += a * wl.x + xv * wr.x;
            o1 += a * wl.y + xv * wr.y;
            o2 += a * wl.z + xv * wr.z;
            o3 += a * wl.w + xv * wr.w;
        }
        o0 = o0 > 0.f ? o0 : 0.01f * o0;
        o1 = o1 > 0.f ? o1 : 0.01f * o1;
        o2 = o2 > 0.f ? o2 : 0.01f * o2;
        o3 = o3 > 0.f ? o3 : 0.01f * o3;
        ushort4 u;
        u.x = f2bf(o0); u.y = f2bf(o1); u.z = f2bf(o2); u.w = f2bf(o3);
        *(ushort4*)(outb + (size_t)node * 64 + c4) = u;
    }
}

// ---- layer-2 GEMM: out = lrelu(agg@Wl + b + hb@Wr), hb bf16, out fp32 ----
__global__ __launch_bounds__(512, 6) void k_gemm32(
    const float* __restrict__ agg, const ushort* __restrict__ hb,
    const float* __restrict__ Wl, const float* __restrict__ bias,
    const float* __restrict__ Wr, float* __restrict__ out, int N) {
    __shared__ float sWl[64 * 32];
    __shared__ float sWr[64 * 32];
    __shared__ float sA[32][68];
    __shared__ float sX[32][68];

    const int tid = threadIdx.x;
    for (int i = tid; i < 512; i += 512) {
        ((float4*)sWl)[i] = ((const float4*)Wl)[i];
        ((float4*)sWr)[i] = ((const float4*)Wr)[i];
    }

    const int g = tid >> 4;
    const int t = tid & 15;
    const int node = blockIdx.x * 32 + g;
    const int c4 = t * 4;

    if (node < N) {
        *(float4*)&sA[g][c4] = *(const float4*)(agg + (size_t)node * 64 + c4);
        const ushort4 u = *(const ushort4*)(hb + (size_t)node * 64 + c4);
        float4 xv;
        xv.x = bf2f(u.x); xv.y = bf2f(u.y); xv.z = bf2f(u.z); xv.w = bf2f(u.w);
        *(float4*)&sX[g][c4] = xv;
    }
    __syncthreads();

    if (node < N) {
        const int c2 = t * 2;
        float o0 = bias[c2], o1 = bias[c2 + 1];
#pragma unroll 8
        for (int k = 0; k < 64; ++k) {
            const float a = sA[g][k];
            const float xv = sX[g][k];
            const float2 wl = *(const float2*)&sWl[k * 32 + c2];
            const float2 wr = *(const float2*)&sWr[k * 32 + c2];
            o0 += a * wl.x + xv * wr.x;
            o1 += a * wl.y + xv * wr.y;
        }
        float2 o;
        o.x = o0 > 0.f ? o0 : 0.01f * o0;
        o.y = o1 > 0.f ? o1 : 0.01f * o1;
        *(float2*)(out + (size_t)node * 32 + c2) = o;
    }
}

static inline size_t align256(size_t v) { return (v + 255) & ~(size_t)255; }

extern "C" void kernel_launch(void* const* d_in, const int* in_sizes, int n_in,
                              void* d_out, int out_size, void* d_ws, size_t ws_size,
                              hipStream_t stream) {
    const float* x   = (const float*)d_in[0];
    const int* edge  = (const int*)d_in[1];   // [2,E] int32
    const float* W1l = (const float*)d_in[2];
    const float* b1  = (const float*)d_in[3];
    const float* W1r = (const float*)d_in[4];
    const float* W2l = (const float*)d_in[5];
    const float* b2  = (const float*)d_in[6];
    const float* W2r = (const float*)d_in[7];
    float* out = (float*)d_out;

    const int N = in_sizes[0] / 64;
    const int E = in_sizes[1] / 2;
    const int* src = edge;
    const int* tgt = edge + E;

    char* ws = (char*)d_ws;
    size_t off = 0;
    int* cnt = (int*)(ws + off);     off = align256(off + (size_t)N * 4);
    float* agg = (float*)(ws + off); off = align256(off + (size_t)N * 64 * 4);
    // 25.6MB region reused over time: pairs (k_b1..k_b2) -> xb (k_cvt..agg1)
    // -> hb (k_gemm64..k_gemm32). All live ranges disjoint.
    const size_t hreg_off = off;     off = align256(off + (size_t)N * 64 * 4);
    ushort* gb = (ushort*)(ws + hreg_off);   // bf16 gather buffer (xb then hb)

    const int nbuck = (N + BNODES - 1) >> BSH;
    const double meanb = (double)E / (double)(nbuck > 0 ? nbuck : 1);
    const bool shape_ok = nbuck >= 1 && nbuck <= 256 &&
                          meanb + 8.0 * sqrt(meanb) + 64.0 <= (double)CAP &&
                          (size_t)nbuck * CAP * 8 <= (size_t)N * 64 * 4;  // pairs fit in hreg

    size_t ob = off;
    int* rowstart = (int*)(ws + ob); ob = align256(ob + (size_t)N * 4);
    int* colsrc   = (int*)(ws + ob); ob = align256(ob + (size_t)nbuck * CAP * 4);
    int* bcnt     = (int*)(ws + ob); ob = align256(ob + 256 * 4);
    const bool use_bucket = shape_ok && ws_size >= ob;

    const int* rowstart_arg;
    const int* cols_arg;

    if (use_bucket) {
        int2* pairs = (int2*)(ws + hreg_off);   // aliases gb region (dies at k_b2)
        k_zero<<<1, 256, 0, stream>>>(bcnt, 256);
        k_b1<<<(E + B1CHUNK - 1) / B1CHUNK, 256, 0, stream>>>(src, tgt, E, bcnt, pairs);
        k_b2<<<nbuck, 512, 0, stream>>>(pairs, bcnt, cnt, rowstart, colsrc, N);
        rowstart_arg = rowstart;
        cols_arg = colsrc;
    } else {
        int* colpad = (int*)(ws + off);
        k_zero<<<512, 256, 0, stream>>>(cnt, N);
        k_build<<<2048, 256, 0, stream>>>(src, tgt, E, cnt, colpad);
        rowstart_arg = nullptr;
        cols_arg = colpad;
    }

    const int nbA = (N + 15) / 16;
    const int nbG = (N + 31) / 32;

    // x -> bf16 (RNE)
    k_cvt<<<2048, 256, 0, stream>>>(x, (ushort*)gb, N * 16);

    // layer 1: gather bf16 x, fp32 GEMM, bf16 h out (fused conversion)
    k_agg<<<nbA, 256, 0, stream>>>(gb, rowstart_arg, cnt, cols_arg, agg, N);
    k_gemm64<<<nbG, 512, 0, stream>>>(agg, x, W1l, b1, W1r, gb, N);
    // layer 2: gather bf16 h, fp32 GEMM, fp32 out
    k_agg<<<nbA, 256, 0, stream>>>(gb, rowstart_arg, cnt, cols_arg, agg, N);
    k_gemm32<<<nbG, 512, 0, stream>>>(agg, gb, W2l, b2, W2r, out, N);
}